// Round 3
// baseline (46.874 us; speedup 1.0000x reference)
//
#include <hip/hip_runtime.h>
#include <math.h>

#define BLK   256
#define MAXF  512     // max frequency bins supported (F = 201 here)
#define SPLIT 8       // chunks per frequency -> F*SPLIT work items
#define ILP   4       // independent rotation chains per thread
// ws layout (floats): [0] counter (as unsigned), [64..) re partials, [64+MAXF*SPLIT..) im partials

// Fused kernel: per-(freq, chunk) partial DFT projection + last-block finalize.
// Angles are exact: k = (f*i) mod fs maintained in integers; rev = k/fs in [0,1)
// feeds v_sin_f32/v_cos_f32 (which take revolutions) with zero range reduction.
// Inner loop uses a 2x2 rotation recurrence (4 FMA) instead of sin/cos:
// chain length is only ~N/(SPLIT*BLK*ILP) ~ 12 steps, so drift is ~1e-6.
__global__ void __launch_bounds__(BLK) extractor_fused_kernel(
    const float* __restrict__ x, int N,
    const int* __restrict__ p_ftrue,
    const int* __restrict__ p_fs,
    const int* __restrict__ p_delta,
    const int* __restrict__ p_fmin,
    const int* __restrict__ p_fmax,
    float* __restrict__ ws,
    unsigned* __restrict__ counter,
    float* __restrict__ out)
{
    const unsigned fs   = (unsigned)*p_fs;
    const int      fmin = *p_fmin;
    const int      fmax = *p_fmax;
    const int      F    = fmax - fmin + 1;
    const float  inv_fs = 1.0f / (float)fs;

    const int Nc = (N + SPLIT - 1) / SPLIT;
    const int W  = F * SPLIT;

    float* re = ws + 64;
    float* im = ws + 64 + MAXF * SPLIT;

    __shared__ float    red[8];
    __shared__ unsigned s_old;

    int done = 0;
    for (int w = blockIdx.x; w < W; w += gridDim.x) {
        const int j     = w >> 3;          // SPLIT == 8
        const int chunk = w & (SPLIT - 1);
        if (j >= MAXF) break;

        const unsigned f   = (unsigned)(fmin + j);
        const int      tid = threadIdx.x;
        const int      i0  = chunk * Nc + tid;
        const int      iend = min(N, (chunk + 1) * Nc);

        // --- exact integer angle setup (cheap: one 32-bit urem/thread) ---
        // uniform: base angle index for this chunk, and per-BLK step
        const unsigned kb = (unsigned)(((unsigned long long)f * (unsigned)(chunk * Nc)) % fs);
        const unsigned sb = (f * (unsigned)BLK) % fs;       // f*256 < 2^31
        // per-thread: k0 = (kb + f*tid) mod fs
        unsigned pt = (f * (unsigned)tid) % fs;
        unsigned k0 = kb + pt; if (k0 >= fs) k0 -= fs;

        unsigned k[ILP];
        k[0] = k0;
        #pragma unroll
        for (int u = 1; u < ILP; ++u) { k[u] = k[u-1] + sb; if (k[u] >= fs) k[u] -= fs; }
        // rotation step angle index for stride ILP*BLK: sL = 4*sb mod fs
        unsigned sL = sb;
        #pragma unroll
        for (int r = 0; r < 2; ++r) { sL += sL; if (sL >= fs) sL -= fs; }

        // initial phasors + rotation constants (the only trans ops: 10 total)
        float c[ILP], s[ILP], ar[ILP], ai[ILP];
        #pragma unroll
        for (int u = 0; u < ILP; ++u) {
            float rev = (float)k[u] * inv_fs;               // [0,1)
            s[u] = __builtin_amdgcn_sinf(rev);              // sin(2*pi*rev)
            c[u] = __builtin_amdgcn_cosf(rev);
            ar[u] = 0.0f; ai[u] = 0.0f;
        }
        float revL = (float)sL * inv_fs;
        const float S = __builtin_amdgcn_sinf(revL);
        const float C = __builtin_amdgcn_cosf(revL);

        int i = i0;
        for (; i + (ILP - 1) * BLK < iend; i += ILP * BLK) {
            #pragma unroll
            for (int u = 0; u < ILP; ++u) {
                float xv = x[i + u * BLK];
                ar[u] = fmaf(xv, c[u], ar[u]);
                ai[u] = fmaf(xv, s[u], ai[u]);
                float cn = fmaf(c[u], C, -(s[u] * S));      // rotate by step
                float sn = fmaf(s[u], C,  (c[u] * S));
                c[u] = cn; s[u] = sn;
            }
        }
        #pragma unroll
        for (int u = 0; u < ILP; ++u) {                     // guarded tail
            int idx = i + u * BLK;
            if (idx < iend) {
                float xv = x[idx];
                ar[u] = fmaf(xv, c[u], ar[u]);
                ai[u] = fmaf(xv, s[u], ai[u]);
            }
        }

        float arS = (ar[0] + ar[1]) + (ar[2] + ar[3]);
        float aiS = (ai[0] + ai[1]) + (ai[2] + ai[3]);

        #pragma unroll
        for (int o = 32; o > 0; o >>= 1) {
            arS += __shfl_down(arS, o, 64);
            aiS += __shfl_down(aiS, o, 64);
        }
        const int lane = tid & 63;
        const int wid  = tid >> 6;
        if (lane == 0) { red[wid * 2] = arS; red[wid * 2 + 1] = aiS; }
        __syncthreads();
        if (tid == 0) {
            re[w] = (red[0] + red[2]) + (red[4] + red[6]);
            im[w] = (red[1] + red[3]) + (red[5] + red[7]);
        }
        __syncthreads();
        ++done;
    }

    // --- last-block finalization (device-scope counter in ws) ---
    if (done) {
        if (threadIdx.x == 0) {
            __threadfence();                                // release partials
            s_old = atomicAdd(counter, (unsigned)done);
        }
        __syncthreads();
        if (s_old + (unsigned)done == (unsigned)W) {        // block-uniform
            __threadfence();                                // acquire partials
            const int ftrue = *p_ftrue;
            const int delta = *p_delta;
            float t1 = 0.0f, t2 = 0.0f;
            for (int j = threadIdx.x; j < F && j < MAXF; j += BLK) {
                float r = 0.0f, m = 0.0f;
                #pragma unroll
                for (int u = 0; u < SPLIT; ++u) {
                    r += re[j * SPLIT + u];
                    m += im[j * SPLIT + u];
                }
                float psd = r * r + m * m;
                int   fq  = fmin + j;
                bool wanted = (fq >= ftrue - delta) && (fq <= ftrue + delta);
                if (wanted) t1 += psd; else t2 += psd;
            }
            #pragma unroll
            for (int o = 32; o > 0; o >>= 1) {
                t1 += __shfl_down(t1, o, 64);
                t2 += __shfl_down(t2, o, 64);
            }
            const int lane2 = threadIdx.x & 63;
            const int wid2  = threadIdx.x >> 6;
            __syncthreads();
            if (lane2 == 0) { red[wid2 * 2] = t1; red[wid2 * 2 + 1] = t2; }
            __syncthreads();
            if (threadIdx.x == 0) {
                float a = (red[0] + red[2]) + (red[4] + red[6]);
                float b = (red[1] + red[3]) + (red[5] + red[7]);
                out[0] = -10.0f * log10f(a / b);
            }
        }
    }
}

extern "C" void kernel_launch(void* const* d_in, const int* in_sizes, int n_in,
                              void* d_out, int out_size, void* d_ws, size_t ws_size,
                              hipStream_t stream) {
    const float* x       = (const float*)d_in[0];
    const int*   p_ftrue = (const int*)d_in[1];
    const int*   p_fs    = (const int*)d_in[2];
    const int*   p_delta = (const int*)d_in[3];
    const int*   p_fmin  = (const int*)d_in[4];
    const int*   p_fmax  = (const int*)d_in[5];
    float*       out     = (float*)d_out;
    float*       ws      = (float*)d_ws;
    unsigned*    counter = (unsigned*)d_ws;
    const int N = in_sizes[0];

    // counter must be 0 at kernel start every call (ws is poisoned once, never re-poisoned)
    hipMemsetAsync(d_ws, 0, sizeof(unsigned), stream);
    // F known only on device; 2048 grid-strided blocks cover F*SPLIT <= 4096
    extractor_fused_kernel<<<2048, BLK, 0, stream>>>(
        x, N, p_ftrue, p_fs, p_delta, p_fmin, p_fmax, ws, counter, out);
}

// Round 4
// 14.506 us; speedup vs baseline: 3.2313x; 3.2313x over previous
//
#include <hip/hip_runtime.h>
#include <math.h>

#define BLK   256
#define MAXF  512     // max frequency bins supported (F = 201 here)
#define SPLIT 8       // chunks per frequency -> F*SPLIT work items
#define ILP   4       // independent rotation chains per thread
// ws layout (floats): [0 .. MAXF*SPLIT) re partials, [MAXF*SPLIT .. 2*MAXF*SPLIT) im partials

// Kernel 1: per-(freq, chunk) partial DFT projection.
// Exact integer angle at chain heads: k = (f*i) mod fs; rev = k/fs in [0,1) feeds
// v_sin_f32/v_cos_f32 (revolution-argument HW trans, zero range reduction).
// Inner loop advances each chain's phasor by a 2x2 rotation (4 FMA-class ops),
// replacing per-element sin/cos. Chain length ~ N/(SPLIT*BLK*ILP) ~ 12 -> drift ~1e-6.
__global__ void __launch_bounds__(BLK) dft_proj_kernel(
    const float* __restrict__ x, int N,
    const int* __restrict__ p_fs,
    const int* __restrict__ p_fmin,
    const int* __restrict__ p_fmax,
    float* __restrict__ ws)
{
    const unsigned fs   = (unsigned)*p_fs;
    const int      fmin = *p_fmin;
    const int      fmax = *p_fmax;
    const int      F    = fmax - fmin + 1;
    const float  inv_fs = 1.0f / (float)fs;

    const int Nc = (N + SPLIT - 1) / SPLIT;
    const int W  = F * SPLIT;

    float* re = ws;
    float* im = ws + MAXF * SPLIT;

    __shared__ float red[8];  // 4 waves x {re, im}

    for (int w = blockIdx.x; w < W; w += gridDim.x) {
        const int j     = w >> 3;          // SPLIT == 8
        const int chunk = w & (SPLIT - 1);
        if (j >= MAXF) break;

        const unsigned f   = (unsigned)(fmin + j);
        const int      tid = threadIdx.x;
        const int      i0  = chunk * Nc + tid;
        const int      iend = min(N, (chunk + 1) * Nc);

        // --- exact integer angle setup (one 32-bit urem per thread) ---
        const unsigned kb = (unsigned)(((unsigned long long)f * (unsigned)(chunk * Nc)) % fs);
        const unsigned sb = (f * (unsigned)BLK) % fs;     // f*256 << 2^31
        unsigned pt = (f * (unsigned)tid) % fs;
        unsigned k0 = kb + pt; if (k0 >= fs) k0 -= fs;

        unsigned k[ILP];
        k[0] = k0;
        #pragma unroll
        for (int u = 1; u < ILP; ++u) { k[u] = k[u-1] + sb; if (k[u] >= fs) k[u] -= fs; }
        unsigned sL = sb;                                  // stride ILP*BLK: 4*sb mod fs
        #pragma unroll
        for (int r = 0; r < 2; ++r) { sL += sL; if (sL >= fs) sL -= fs; }

        // initial phasors + rotation constants: 10 trans ops total per work item
        float c[ILP], s[ILP], ar[ILP], ai[ILP];
        #pragma unroll
        for (int u = 0; u < ILP; ++u) {
            float rev = (float)k[u] * inv_fs;              // [0,1)
            s[u] = __builtin_amdgcn_sinf(rev);             // sin(2*pi*rev)
            c[u] = __builtin_amdgcn_cosf(rev);
            ar[u] = 0.0f; ai[u] = 0.0f;
        }
        float revL = (float)sL * inv_fs;
        const float S = __builtin_amdgcn_sinf(revL);
        const float C = __builtin_amdgcn_cosf(revL);

        int i = i0;
        for (; i + (ILP - 1) * BLK < iend; i += ILP * BLK) {
            #pragma unroll
            for (int u = 0; u < ILP; ++u) {
                float xv = x[i + u * BLK];
                ar[u] = fmaf(xv, c[u], ar[u]);
                ai[u] = fmaf(xv, s[u], ai[u]);
                float cn = fmaf(c[u], C, -(s[u] * S));     // rotate phasor by step
                float sn = fmaf(s[u], C,  (c[u] * S));
                c[u] = cn; s[u] = sn;
            }
        }
        #pragma unroll
        for (int u = 0; u < ILP; ++u) {                    // guarded tail (<= 1 pass)
            int idx = i + u * BLK;
            if (idx < iend) {
                float xv = x[idx];
                ar[u] = fmaf(xv, c[u], ar[u]);
                ai[u] = fmaf(xv, s[u], ai[u]);
            }
        }

        float arS = (ar[0] + ar[1]) + (ar[2] + ar[3]);
        float aiS = (ai[0] + ai[1]) + (ai[2] + ai[3]);

        // wave butterfly reduce (64 lanes)
        #pragma unroll
        for (int o = 32; o > 0; o >>= 1) {
            arS += __shfl_down(arS, o, 64);
            aiS += __shfl_down(aiS, o, 64);
        }
        const int lane = tid & 63;
        const int wid  = tid >> 6;
        if (lane == 0) { red[wid * 2] = arS; red[wid * 2 + 1] = aiS; }
        __syncthreads();
        if (tid == 0) {
            re[w] = (red[0] + red[2]) + (red[4] + red[6]);
            im[w] = (red[1] + red[3]) + (red[5] + red[7]);
        }
        __syncthreads();  // protect red[] before next grid-stride iteration
    }
}

// Kernel 2: fold SPLIT partials per freq, psd, band split, loss.
__global__ void __launch_bounds__(BLK) loss_kernel(
    const float* __restrict__ ws,
    const int* __restrict__ p_ftrue,
    const int* __restrict__ p_delta,
    const int* __restrict__ p_fmin,
    const int* __restrict__ p_fmax,
    float* __restrict__ out)
{
    const int ftrue = *p_ftrue;
    const int delta = *p_delta;
    const int fmin  = *p_fmin;
    const int fmax  = *p_fmax;
    const int F     = fmax - fmin + 1;

    float t1 = 0.0f, t2 = 0.0f;
    for (int j = threadIdx.x; j < F && j < MAXF; j += BLK) {
        float r = 0.0f, m = 0.0f;
        #pragma unroll
        for (int u = 0; u < SPLIT; ++u) {
            r += ws[j * SPLIT + u];
            m += ws[MAXF * SPLIT + j * SPLIT + u];
        }
        float psd = r * r + m * m;
        int   fq  = fmin + j;
        bool wanted = (fq >= ftrue - delta) && (fq <= ftrue + delta);
        if (wanted) t1 += psd; else t2 += psd;
    }

    __shared__ float red[8];
    #pragma unroll
    for (int o = 32; o > 0; o >>= 1) {
        t1 += __shfl_down(t1, o, 64);
        t2 += __shfl_down(t2, o, 64);
    }
    const int lane = threadIdx.x & 63;
    const int wid  = threadIdx.x >> 6;
    if (lane == 0) { red[wid * 2] = t1; red[wid * 2 + 1] = t2; }
    __syncthreads();
    if (threadIdx.x == 0) {
        float a = (red[0] + red[2]) + (red[4] + red[6]);
        float b = (red[1] + red[3]) + (red[5] + red[7]);
        out[0] = -10.0f * log10f(a / b);
    }
}

extern "C" void kernel_launch(void* const* d_in, const int* in_sizes, int n_in,
                              void* d_out, int out_size, void* d_ws, size_t ws_size,
                              hipStream_t stream) {
    const float* x       = (const float*)d_in[0];
    const int*   p_ftrue = (const int*)d_in[1];
    const int*   p_fs    = (const int*)d_in[2];
    const int*   p_delta = (const int*)d_in[3];
    const int*   p_fmin  = (const int*)d_in[4];
    const int*   p_fmax  = (const int*)d_in[5];
    float*       out     = (float*)d_out;
    float*       ws      = (float*)d_ws;
    const int N = in_sizes[0];

    // F known only on device; 2048 grid-strided blocks cover F*SPLIT <= 4096
    // (F=201 -> 1608 live blocks ~ 6/CU ~ 24 waves/CU).
    dft_proj_kernel<<<2048, BLK, 0, stream>>>(x, N, p_fs, p_fmin, p_fmax, ws);
    loss_kernel<<<1, BLK, 0, stream>>>(ws, p_ftrue, p_delta, p_fmin, p_fmax, out);
}

// Round 5
// 12.578 us; speedup vs baseline: 3.7267x; 1.1533x over previous
//
#include <hip/hip_runtime.h>
#include <math.h>

#define BLK   256
#define MAXF  512     // max frequency bins supported (F = 201 here)
#define SPLIT 4       // chunks per frequency -> F*SPLIT work items (804 blocks)
// ws layout (floats): [0 .. MAXF*SPLIT) re partials, [MAXF*SPLIT .. 2*MAXF*SPLIT) im partials

// fast (a mod fs) for a < 2^31, fs known per-call; +-1 corrections cover fp error
__device__ __forceinline__ unsigned umod_fast(unsigned a, unsigned fs, float inv_fs) {
    unsigned q = (unsigned)((float)a * inv_fs);
    int r = (int)a - (int)(q * fs);
    if (r < 0) r += (int)fs;
    if (r < 0) r += (int)fs;
    if (r >= (int)fs) r -= (int)fs;
    if (r >= (int)fs) r -= (int)fs;
    return (unsigned)r;
}

// Kernel 1: per-(freq, chunk) partial DFT projection, polyphase-4.
// Exact integer angles at chain heads: k = (f*i) mod fs; rev = k/fs in [0,1) feeds
// v_sin_f32/v_cos_f32 (revolution-argument HW trans, zero range reduction).
// Polyphase: 4 consecutive elements share one phasor R^b; accumulate into A_p
// (p = 0..3) and apply twiddles R^p once at the end: sum = sum_p R^p A_p.
// Inner cost: 3 VALU ops/element + 1 dwordx4 load / 4 elements.
__global__ void __launch_bounds__(BLK) dft_proj_kernel(
    const float* __restrict__ x, int N,
    const int* __restrict__ p_fs,
    const int* __restrict__ p_fmin,
    const int* __restrict__ p_fmax,
    float* __restrict__ ws)
{
    const unsigned fs   = (unsigned)*p_fs;
    const int      fmin = *p_fmin;
    const int      fmax = *p_fmax;
    const int      F    = fmax - fmin + 1;
    const float  inv_fs = 1.0f / (float)fs;

    int Nc = (N + SPLIT - 1) / SPLIT;
    Nc = (Nc + 3) & ~3;                       // multiple of 4 -> float4-aligned chunks
    const int W = F * SPLIT;

    float* re = ws;
    float* im = ws + MAXF * SPLIT;

    __shared__ float red[8];  // 4 waves x {re, im}

    for (int w = blockIdx.x; w < W; w += gridDim.x) {
        const int j     = w >> 2;             // SPLIT == 4
        const int chunk = w & (SPLIT - 1);
        if (j >= MAXF) break;

        const unsigned f   = (unsigned)(fmin + j);
        const int      tid = threadIdx.x;
        const int      cs   = chunk * Nc;     // chunk start (multiple of 4)
        const int      iend = min(N, cs + Nc);

        // --- exact integer angle setup ---
        const unsigned kb = (unsigned)(((unsigned long long)f * (unsigned)cs) % fs);   // uniform
        unsigned pt = umod_fast(f * (unsigned)(4 * tid), fs, inv_fs);                  // per-thread
        unsigned k0 = kb + pt; if (k0 >= fs) k0 -= fs;                                 // angle of b0
        const unsigned k4 = (unsigned)(((unsigned long long)f * (unsigned)(4 * BLK)) % fs); // stride 4*BLK
        const unsigned kf = (f >= fs) ? (f % fs) : f;                                  // stride 1

        // phasors / rotation constants (6 trans ops per work item)
        float cA = __builtin_amdgcn_cosf((float)k0 * inv_fs);
        float sA = __builtin_amdgcn_sinf((float)k0 * inv_fs);
        const float C4 = __builtin_amdgcn_cosf((float)k4 * inv_fs);
        const float S4 = __builtin_amdgcn_sinf((float)k4 * inv_fs);
        float cB = fmaf(cA, C4, -(sA * S4));   // phasor at b0 + 4*BLK
        float sB = fmaf(sA, C4,  (cA * S4));
        const float C8 = fmaf(C4, C4, -(S4 * S4));   // rotation for stride 8*BLK
        const float S8 = 2.0f * C4 * S4;

        // 4 polyphase complex accumulators
        float a0r = 0.f, a0i = 0.f, a1r = 0.f, a1i = 0.f;
        float a2r = 0.f, a2i = 0.f, a3r = 0.f, a3i = 0.f;

        int b = cs + 4 * tid;
        // main loop: two float4 groups (A at b, B at b+4*BLK) per iteration
        for (; b + 4 * BLK + 4 <= iend; b += 8 * BLK) {
            float4 xa = *reinterpret_cast<const float4*>(x + b);
            float4 xb = *reinterpret_cast<const float4*>(x + b + 4 * BLK);
            a0r = fmaf(xa.x, cA, a0r); a0i = fmaf(xa.x, sA, a0i);
            a1r = fmaf(xa.y, cA, a1r); a1i = fmaf(xa.y, sA, a1i);
            a2r = fmaf(xa.z, cA, a2r); a2i = fmaf(xa.z, sA, a2i);
            a3r = fmaf(xa.w, cA, a3r); a3i = fmaf(xa.w, sA, a3i);
            a0r = fmaf(xb.x, cB, a0r); a0i = fmaf(xb.x, sB, a0i);
            a1r = fmaf(xb.y, cB, a1r); a1i = fmaf(xb.y, sB, a1i);
            a2r = fmaf(xb.z, cB, a2r); a2i = fmaf(xb.z, sB, a2i);
            a3r = fmaf(xb.w, cB, a3r); a3i = fmaf(xb.w, sB, a3i);
            float cn = fmaf(cA, C8, -(sA * S8));
            float sn = fmaf(sA, C8,  (cA * S8));
            cA = cn; sA = sn;
            cn = fmaf(cB, C8, -(sB * S8));
            sn = fmaf(sB, C8,  (cB * S8));
            cB = cn; sB = sn;
        }
        // guarded tails: at most one group each for A and B positions
        #pragma unroll
        for (int p = 0; p < 4; ++p) {
            int idx = b + p;
            if (idx < iend) {
                float xv = x[idx];
                if (p == 0) { a0r = fmaf(xv, cA, a0r); a0i = fmaf(xv, sA, a0i); }
                if (p == 1) { a1r = fmaf(xv, cA, a1r); a1i = fmaf(xv, sA, a1i); }
                if (p == 2) { a2r = fmaf(xv, cA, a2r); a2i = fmaf(xv, sA, a2i); }
                if (p == 3) { a3r = fmaf(xv, cA, a3r); a3i = fmaf(xv, sA, a3i); }
            }
        }
        #pragma unroll
        for (int p = 0; p < 4; ++p) {
            int idx = b + 4 * BLK + p;
            if (idx < iend) {
                float xv = x[idx];
                if (p == 0) { a0r = fmaf(xv, cB, a0r); a0i = fmaf(xv, sB, a0i); }
                if (p == 1) { a1r = fmaf(xv, cB, a1r); a1i = fmaf(xv, sB, a1i); }
                if (p == 2) { a2r = fmaf(xv, cB, a2r); a2i = fmaf(xv, sB, a2i); }
                if (p == 3) { a3r = fmaf(xv, cB, a3r); a3i = fmaf(xv, sB, a3i); }
            }
        }

        // twiddle combine: sum = A0 + R^1 A1 + R^2 A2 + R^3 A3  (R = e^{i 2pi f/fs})
        const float c1 = __builtin_amdgcn_cosf((float)kf * inv_fs);
        const float s1 = __builtin_amdgcn_sinf((float)kf * inv_fs);
        const float c2 = fmaf(c1, c1, -(s1 * s1));
        const float s2 = 2.0f * c1 * s1;
        const float c3 = fmaf(c2, c1, -(s2 * s1));
        const float s3 = fmaf(s2, c1,  (c2 * s1));
        float arS = a0r, aiS = a0i;
        arS = fmaf(c1, a1r, arS); arS = fmaf(-s1, a1i, arS);
        aiS = fmaf(c1, a1i, aiS); aiS = fmaf( s1, a1r, aiS);
        arS = fmaf(c2, a2r, arS); arS = fmaf(-s2, a2i, arS);
        aiS = fmaf(c2, a2i, aiS); aiS = fmaf( s2, a2r, aiS);
        arS = fmaf(c3, a3r, arS); arS = fmaf(-s3, a3i, arS);
        aiS = fmaf(c3, a3i, aiS); aiS = fmaf( s3, a3r, aiS);

        // wave butterfly reduce (64 lanes)
        #pragma unroll
        for (int o = 32; o > 0; o >>= 1) {
            arS += __shfl_down(arS, o, 64);
            aiS += __shfl_down(aiS, o, 64);
        }
        const int lane = tid & 63;
        const int wid  = tid >> 6;
        if (lane == 0) { red[wid * 2] = arS; red[wid * 2 + 1] = aiS; }
        __syncthreads();
        if (tid == 0) {
            re[w] = (red[0] + red[2]) + (red[4] + red[6]);
            im[w] = (red[1] + red[3]) + (red[5] + red[7]);
        }
        __syncthreads();  // protect red[] before next grid-stride iteration
    }
}

// Kernel 2: fold SPLIT partials per freq, psd, band split, loss.
__global__ void __launch_bounds__(BLK) loss_kernel(
    const float* __restrict__ ws,
    const int* __restrict__ p_ftrue,
    const int* __restrict__ p_delta,
    const int* __restrict__ p_fmin,
    const int* __restrict__ p_fmax,
    float* __restrict__ out)
{
    const int ftrue = *p_ftrue;
    const int delta = *p_delta;
    const int fmin  = *p_fmin;
    const int fmax  = *p_fmax;
    const int F     = fmax - fmin + 1;

    float t1 = 0.0f, t2 = 0.0f;
    for (int j = threadIdx.x; j < F && j < MAXF; j += BLK) {
        float r = 0.0f, m = 0.0f;
        #pragma unroll
        for (int u = 0; u < SPLIT; ++u) {
            r += ws[j * SPLIT + u];
            m += ws[MAXF * SPLIT + j * SPLIT + u];
        }
        float psd = r * r + m * m;
        int   fq  = fmin + j;
        bool wanted = (fq >= ftrue - delta) && (fq <= ftrue + delta);
        if (wanted) t1 += psd; else t2 += psd;
    }

    __shared__ float red[8];
    #pragma unroll
    for (int o = 32; o > 0; o >>= 1) {
        t1 += __shfl_down(t1, o, 64);
        t2 += __shfl_down(t2, o, 64);
    }
    const int lane = threadIdx.x & 63;
    const int wid  = threadIdx.x >> 6;
    if (lane == 0) { red[wid * 2] = t1; red[wid * 2 + 1] = t2; }
    __syncthreads();
    if (threadIdx.x == 0) {
        float a = (red[0] + red[2]) + (red[4] + red[6]);
        float b = (red[1] + red[3]) + (red[5] + red[7]);
        out[0] = -10.0f * log10f(a / b);
    }
}

extern "C" void kernel_launch(void* const* d_in, const int* in_sizes, int n_in,
                              void* d_out, int out_size, void* d_ws, size_t ws_size,
                              hipStream_t stream) {
    const float* x       = (const float*)d_in[0];
    const int*   p_ftrue = (const int*)d_in[1];
    const int*   p_fs    = (const int*)d_in[2];
    const int*   p_delta = (const int*)d_in[3];
    const int*   p_fmin  = (const int*)d_in[4];
    const int*   p_fmax  = (const int*)d_in[5];
    float*       out     = (float*)d_out;
    float*       ws      = (float*)d_ws;
    const int N = in_sizes[0];

    // F known only on device; 1024 grid-strided blocks cover F*SPLIT <= 2048
    // (F=201 -> 804 live blocks ~ 3/CU ~ 12 waves/CU).
    dft_proj_kernel<<<1024, BLK, 0, stream>>>(x, N, p_fs, p_fmin, p_fmax, ws);
    loss_kernel<<<1, BLK, 0, stream>>>(ws, p_ftrue, p_delta, p_fmin, p_fmax, out);
}